// Round 2
// baseline (545.478 us; speedup 1.0000x reference)
//
#include <hip/hip_runtime.h>

#define S 256
#define H 64
#define ROWS 256      // rows per block (= blockDim.x, 1 row per thread)
#define CC 32         // column chunk for both phases (8 float4 units)

// LDS per block: 2 * 256*32*4 = 64 KB -> 2 blocks/CU (128 KB of 160 KB)
__global__ __launch_bounds__(256, 2)
void fused_mvn_kernel(const float* __restrict__ x,
                      const float* __restrict__ eps,
                      const float* __restrict__ W1,
                      const float* __restrict__ b1,
                      const float* __restrict__ W2,
                      const float* __restrict__ b2,
                      float* __restrict__ out)
{
    __shared__ float ldsA[ROWS * CC];   // x-tile, then out-tile (32 KB)
    __shared__ float ldsB[ROWS * CC];   // eps-tile (32 KB)
    float4* lds4A = (float4*)ldsA;
    float4* lds4B = (float4*)ldsB;

    const int tid = threadIdx.x;
    const int r = tid;                               // this thread's row in block
    const long long row0 = (long long)blockIdx.x * ROWS;

    // h accumulators, init with b1 (uniform -> s_load)
    float h[H];
#pragma unroll
    for (int j = 0; j < H; ++j) h[j] = b1[j];

    // ---------------- Phase 1: h = x @ W1 + b1 ----------------
    for (int kc = 0; kc < S; kc += CC) {
        __syncthreads();   // prior consumers of ldsA done
        // stage x[row0..row0+255][kc..kc+31] -> ldsA, coalesced, XOR swizzle on 16B units
#pragma unroll
        for (int i = 0; i < 8; ++i) {
            int e4  = i * 256 + tid;       // 0..2047 float4 tile elements
            int row = e4 >> 3;             // 8 units per row
            int u   = e4 & 7;
            float4 v = *(const float4*)(x + (row0 + row) * S + kc + u * 4);
            lds4A[row * 8 + (u ^ (row & 7))] = v;
        }
        __syncthreads();
        // consume: thread r walks its own row; W1 is uniform -> SGPR operand fmacs
#pragma unroll
        for (int u = 0; u < 8; ++u) {
            float4 xv = lds4A[r * 8 + (u ^ (r & 7))];
            float xs[4] = {xv.x, xv.y, xv.z, xv.w};
#pragma unroll
            for (int kk = 0; kk < 4; ++kk) {
                const float* w = W1 + (kc + u * 4 + kk) * H;
#pragma unroll
                for (int j = 0; j < H; ++j)
                    h[j] = fmaf(xs[kk], w[j], h[j]);
            }
        }
    }

    // relu, then fold 0.5*log2(e) so phase-2 epilogue is a single v_exp_f32 (exp2)
    const float chalf = 0.7213475204444817f;   // 0.5 * log2(e)
#pragma unroll
    for (int j = 0; j < H; ++j) h[j] = fmaxf(h[j], 0.0f) * chalf;

    // ---------------- Phase 2: out = x + exp2((h@W2 + b2)*c) * eps ----------------
    for (int sc = 0; sc < S; sc += CC) {
        __syncthreads();   // prior chunk's cooperative store done
        // stage x and eps tiles for cols sc..sc+31
#pragma unroll
        for (int i = 0; i < 8; ++i) {
            int e4  = i * 256 + tid;
            int row = e4 >> 3;
            int u   = e4 & 7;
            long long g = (row0 + row) * S + sc + u * 4;
            int slot = row * 8 + (u ^ (row & 7));
            lds4A[slot] = *(const float4*)(x + g);
            lds4B[slot] = *(const float4*)(eps + g);
        }
        __syncthreads();

        // logits for this thread's row, cols sc..sc+31; W2 rows uniform -> SGPR fmacs
        float acc[CC];
#pragma unroll
        for (int i = 0; i < CC; ++i) acc[i] = b2[sc + i] * chalf;
#pragma unroll
        for (int j = 0; j < H; ++j) {
            const float hj = h[j];
            const float* w = W2 + j * S + sc;
#pragma unroll
            for (int i = 0; i < CC; ++i)
                acc[i] = fmaf(hj, w[i], acc[i]);
        }

        // epilogue: o = x + exp2(acc) * eps, write back into ldsA (own row only)
#pragma unroll
        for (int u = 0; u < 8; ++u) {
            int slot = r * 8 + (u ^ (r & 7));
            float4 xv = lds4A[slot];
            float4 ev = lds4B[slot];
            float4 o;
            o.x = fmaf(__builtin_amdgcn_exp2f(acc[u * 4 + 0]), ev.x, xv.x);
            o.y = fmaf(__builtin_amdgcn_exp2f(acc[u * 4 + 1]), ev.y, xv.y);
            o.z = fmaf(__builtin_amdgcn_exp2f(acc[u * 4 + 2]), ev.z, xv.z);
            o.w = fmaf(__builtin_amdgcn_exp2f(acc[u * 4 + 3]), ev.w, xv.w);
            lds4A[slot] = o;
        }
        __syncthreads();
        // cooperative coalesced store of the out-tile
#pragma unroll
        for (int i = 0; i < 8; ++i) {
            int e4  = i * 256 + tid;
            int row = e4 >> 3;
            int u   = e4 & 7;
            float4 v = lds4A[row * 8 + (u ^ (row & 7))];
            *(float4*)(out + (row0 + row) * S + sc + u * 4) = v;
        }
    }
}

extern "C" void kernel_launch(void* const* d_in, const int* in_sizes, int n_in,
                              void* d_out, int out_size, void* d_ws, size_t ws_size,
                              hipStream_t stream) {
    const float* x   = (const float*)d_in[0];
    const float* eps = (const float*)d_in[1];
    const float* W1  = (const float*)d_in[2];
    const float* b1  = (const float*)d_in[3];
    const float* W2  = (const float*)d_in[4];
    const float* b2  = (const float*)d_in[5];
    float* out = (float*)d_out;

    const int B = in_sizes[0] / S;          // 131072
    dim3 grid(B / ROWS);                    // 512 blocks
    dim3 block(256);
    hipLaunchKernelGGL(fused_mvn_kernel, grid, block, 0, stream,
                       x, eps, W1, b1, W2, b2, out);
}